// Round 9
// baseline (139.744 us; speedup 1.0000x reference)
//
#include <hip/hip_runtime.h>
#include <hip/hip_bf16.h>

#define BB 8192
#define DD 256
#define ZN (2 * BB)   // floats to zero: S_all, S_1

typedef float f32x4 __attribute__((ext_vector_type(4)));
typedef __bf16 bf16x8 __attribute__((ext_vector_type(8)));

// sqrt(log2(e)/0.07): fn rows pre-scaled so MFMA acc = sim * log2(e)/T directly
#define FSCALE 4.53981600f

// raw v_exp_f32: args here are |x| <= ~21, no range fixup needed
__device__ __forceinline__ float fast_exp2(float x) {
    float r;
    asm("v_exp_f32 %0, %1" : "=v"(r) : "v"(x));
    return r;
}

// ---------------------------------------------------------------------------
// prep: one wave per row. dist_sq vs center, sigma partials (block-reduced,
// race-free into stats_part[block]), writes the normalized+scaled row in MFMA
// FRAGMENT ORDER. Also zeroes S_all/S_1/out.
// ---------------------------------------------------------------------------
__global__ __launch_bounds__(256) void prep_kernel(
    const float* __restrict__ feat, const int* __restrict__ labels,
    const float* __restrict__ center, __hip_bfloat16* __restrict__ fnf,
    float* __restrict__ dist_sq, float* __restrict__ stats_part,
    float* __restrict__ zacc, float* __restrict__ out)
{
    __shared__ float sh[3][4];
    const int gid = blockIdx.x * 256 + threadIdx.x;
    if (gid < ZN) zacc[gid] = 0.0f;
    if (gid == 0) out[0] = 0.0f;

    const int wave = threadIdx.x >> 6;
    const int lane = threadIdx.x & 63;
    const int row  = blockIdx.x * 4 + wave;

    const float4* frow = reinterpret_cast<const float4*>(feat + (size_t)row * DD);
    const float4* crow = reinterpret_cast<const float4*>(center);
    float4 x = frow[lane];
    float4 c = crow[lane];

    float d0 = x.x - c.x, d1 = x.y - c.y, d2 = x.z - c.z, d3 = x.w - c.w;
    float dsq = d0*d0 + d1*d1 + d2*d2 + d3*d3;
    float nsq = x.x*x.x + x.y*x.y + x.z*x.z + x.w*x.w;
    float sx  = x.x + x.y + x.z + x.w;

    #pragma unroll
    for (int m = 1; m < 64; m <<= 1) {
        dsq += __shfl_xor(dsq, m);
        nsq += __shfl_xor(nsq, m);
        sx  += __shfl_xor(sx,  m);
    }

    float rn = FSCALE / fmaxf(sqrtf(nsq), 1e-12f);

    ushort4 u;
    u.x = __builtin_bit_cast(unsigned short, __float2bfloat16(x.x * rn));
    u.y = __builtin_bit_cast(unsigned short, __float2bfloat16(x.y * rn));
    u.z = __builtin_bit_cast(unsigned short, __float2bfloat16(x.z * rn));
    u.w = __builtin_bit_cast(unsigned short, __float2bfloat16(x.w * rn));

    // lane holds elems e=4*lane..+3: kc=lane/8, quad=(lane%8)/2, half=lane&1
    const int g    = row >> 4;
    const int l15r = row & 15;
    const int kc   = lane >> 3;
    const int qd   = (lane & 7) >> 1;
    const int half = lane & 1;
    const size_t cell = (size_t)((g * 8 + kc) * 64 + qd * 16 + l15r);
    reinterpret_cast<ushort4*>(fnf)[cell * 2 + half] = u;

    if (lane == 0) {
        const float m0 = (labels[row] == 0) ? 1.0f : 0.0f;
        dist_sq[row] = dsq;
        sh[0][wave] = m0;
        sh[1][wave] = sx  * m0;
        sh[2][wave] = nsq * m0;
    }
    __syncthreads();
    if (threadIdx.x == 0) {
        float* sp = stats_part + (size_t)blockIdx.x * 4;
        sp[0] = sh[0][0] + sh[0][1] + sh[0][2] + sh[0][3];
        sp[1] = sh[1][0] + sh[1][1] + sh[1][2] + sh[1][3];
        sp[2] = sh[2][0] + sh[2][1] + sh[2][2] + sh[2][3];
        sp[3] = 0.0f;
    }
}

// ---------------------------------------------------------------------------
// gram v10: v9's symmetric cells (numerics proven, absmax 0), rebalanced.
// v9 diagnosis: regression = 5th ragged round (1056 blocks, +25%) + col-side
// epilogue overhead; MFMA work correctly halved (MfmaUtil 29->12.5%).
// v10: grid EXACTLY 1024 (4/CU, uniform rounds). Cells 0..1023 -> blocks
// 1:1; leftover cells 1024..1055 (all upper, panel c=31) split into 128
// four-tile slices appended to blocks 0..127 (+4 tiles spread over ~128
// CUs ~ +6% instead of +25%). run_cell(t0, nt) = v9 pipeline verbatim.
// Diag cells' far tiles skip col-side VALU (3-way uniform branch).
// ---------------------------------------------------------------------------
#define LOAD4(BV, T, KB)                                                       \
  {                                                                            \
    _Pragma("unroll")                                                          \
    for (int k = 0; k < 4; ++k)                                                \
      BV[k] = F[((size_t)(cpanel + (T)) * 8 + (KB) + k) * 64 + lane];          \
  }

#define MFMA8(BV, KB)                                                          \
  {                                                                            \
    _Pragma("unroll")                                                          \
    for (int k = 0; k < 4; ++k) {                                              \
      acc[0] = __builtin_amdgcn_mfma_f32_16x16x32_bf16(a[0][(KB) + k], BV[k], acc[0], 0, 0, 0); \
      acc[1] = __builtin_amdgcn_mfma_f32_16x16x32_bf16(a[1][(KB) + k], BV[k], acc[1], 0, 0, 0); \
    }                                                                          \
  }

// T = cell-local tile index (0..nt-1); absolute tile = t0 + T
#define EPILOGUE(T)                                                            \
  {                                                                            \
    const int colbase = colstart + (t0 + (T)) * 16;                            \
    const int bcol = colbase + l15;                                            \
    const float w1 = wlab[(T) * 16 + l15];                                     \
    if (isdiag && colbase + 16 > rowbase && colbase < rowbase + 32) {          \
      _Pragma("unroll")                                                        \
      for (int s = 0; s < 2; ++s)                                              \
        _Pragma("unroll")                                                      \
        for (int rr = 0; rr < 4; ++rr) {                                       \
          const int rq = rowbase + s * 16 + quad * 4 + rr;                     \
          float e = (rq == bcol) ? 0.0f : fast_exp2(acc[s][rr]);               \
          sall[s][rr] += e; sp1[s][rr] = fmaf(e, w1, sp1[s][rr]);              \
        }                                                                      \
    } else if (!isdiag) {                                                      \
      float ca = 0.0f, c1 = 0.0f;                                              \
      _Pragma("unroll")                                                        \
      for (int s = 0; s < 2; ++s)                                              \
        _Pragma("unroll")                                                      \
        for (int rr = 0; rr < 4; ++rr) {                                       \
          float e = fast_exp2(acc[s][rr]);                                     \
          sall[s][rr] += e; sp1[s][rr] = fmaf(e, w1, sp1[s][rr]);              \
          ca += e; c1 = fmaf(e, wr[s][rr], c1);                                \
        }                                                                      \
      ca += __shfl_xor(ca, 16); ca += __shfl_xor(ca, 32);                      \
      c1 += __shfl_xor(c1, 16); c1 += __shfl_xor(c1, 32);                      \
      if (quad == 0) {                                                         \
        atomicAdd(&S_all[bcol], ca);                                           \
        atomicAdd(&S_1[bcol],  c1);                                            \
      }                                                                        \
    } else {                                                                   \
      _Pragma("unroll")                                                        \
      for (int s = 0; s < 2; ++s)                                              \
        _Pragma("unroll")                                                      \
        for (int rr = 0; rr < 4; ++rr) {                                       \
          float e = fast_exp2(acc[s][rr]);                                     \
          sall[s][rr] += e; sp1[s][rr] = fmaf(e, w1, sp1[s][rr]);              \
        }                                                                      \
    }                                                                          \
  }

__device__ __forceinline__ void decode_cell(int cid, int& r, int& c, bool& isdiag)
{
    if (cid < 64) { r = cid; c = cid >> 1; isdiag = true; }
    else {
        const int e = cid - 64;
        int c0 = (int)((1.0f + sqrtf(1.0f + 4.0f * (float)e)) * 0.5f);
        while (c0 * (c0 - 1) > e) --c0;
        while ((c0 + 1) * c0 <= e) ++c0;
        c = c0; r = e - c0 * (c0 - 1); isdiag = false;
    }
}

// process tiles [t0, t0+nt) of cell (rcell, ccell). wlab[0..nt*16) must hold
// labels[colstart + t0*16 + i] (block-wide, barriered before call).
__device__ __forceinline__ void run_cell(
    const bf16x8* __restrict__ F, const int* __restrict__ labels,
    float* __restrict__ S_all, float* __restrict__ S_1,
    const float* wlab, int rcell, int ccell, bool isdiag, int t0, int nt,
    int lane, int l15, int quad, int wave)
{
    const int rowbase  = rcell * 128 + wave * 32;
    const int colstart = ccell * 256;
    const int cpanel   = (colstart >> 4) + t0;   // first tile cell-group

    // A fragments: 2 sub-tiles x 8 k-chunks = 32 rows/wave, coalesced loads
    bf16x8 a[2][8];
    #pragma unroll
    for (int s = 0; s < 2; ++s)
        #pragma unroll
        for (int kc = 0; kc < 8; ++kc)
            a[s][kc] = F[(size_t)((((rowbase >> 4) + s) * 8 + kc)) * 64 + lane];

    // row labels for this lane's 8 accumulator rows (col-side S_1 weights)
    float wr[2][4];
    #pragma unroll
    for (int s = 0; s < 2; ++s)
        #pragma unroll
        for (int rr = 0; rr < 4; ++rr)
            wr[s][rr] = (float)labels[rowbase + s * 16 + quad * 4 + rr];

    float sall[2][4], sp1[2][4];
    #pragma unroll
    for (int s = 0; s < 2; ++s)
        #pragma unroll
        for (int rr = 0; rr < 4; ++rr) { sall[s][rr] = 0.0f; sp1[s][rr] = 0.0f; }

    f32x4 acc[2];
    bf16x8 bvP[4], bvC[4];  // fixed roles: bvP = lo(next), bvC = hi(current)

    LOAD4(bvP, 0, 0);       // prefetch first tile lo-half

    #pragma unroll 1
    for (int t = 0; t < nt - 1; ++t) {
        LOAD4(bvC, t, 4);           // current hi-half, in flight under MFMA-lo
        acc[0] = (f32x4){0,0,0,0}; acc[1] = (f32x4){0,0,0,0};
        MFMA8(bvP, 0);              // consume lo (prefetched last tile)
        LOAD4(bvP, t + 1, 0);       // prefetch next lo (WAR: after consume)
        MFMA8(bvC, 4);              // vmcnt wait for bvC folds under MFMA-lo
        EPILOGUE(t);
    }
    // last tile
    LOAD4(bvC, nt - 1, 4);
    acc[0] = (f32x4){0,0,0,0}; acc[1] = (f32x4){0,0,0,0};
    MFMA8(bvP, 0);
    MFMA8(bvC, 4);
    EPILOGUE(nt - 1);

    // row-side: reduce over the 16 cols held across low lane bits
    #pragma unroll
    for (int s = 0; s < 2; ++s)
        #pragma unroll
        for (int rr = 0; rr < 4; ++rr) {
            float va = sall[s][rr];
            float v1 = sp1[s][rr];
            #pragma unroll
            for (int m = 1; m < 16; m <<= 1) {
                va += __shfl_xor(va, m);
                v1 += __shfl_xor(v1, m);
            }
            if (l15 == 0) {
                const int grow = rowbase + s * 16 + quad * 4 + rr;
                atomicAdd(&S_all[grow], va);
                atomicAdd(&S_1[grow],  v1);
            }
        }
}

__global__ __launch_bounds__(256, 4) void gram_kernel(
    const __hip_bfloat16* __restrict__ fnf, const int* __restrict__ labels,
    float* __restrict__ S_all, float* __restrict__ S_1)
{
    __shared__ float wlab[256];

    const int tid  = threadIdx.x;
    const int lane = tid & 63;
    const int wave = tid >> 6;
    const int l15  = lane & 15;
    const int quad = lane >> 4;
    const int bid  = blockIdx.x;

    const bf16x8* __restrict__ F = reinterpret_cast<const bf16x8*>(fnf);

    // ---- main cell: cid = bid (0..1023), full 16 tiles ----
    int r, c; bool isdiag;
    decode_cell(bid, r, c, isdiag);

    wlab[tid] = (float)labels[c * 256 + tid];   // 256 threads = 256 cols
    __syncthreads();

    run_cell(F, labels, S_all, S_1, wlab, r, c, isdiag, 0, 16,
             lane, l15, quad, wave);

    // ---- slice: blocks 0..127 also do 4 tiles of cells 1024..1055 ----
    if (bid < 128) {
        int r2, c2; bool d2;
        decode_cell(1024 + (bid >> 2), r2, c2, d2);   // always upper
        const int t0 = (bid & 3) * 4;

        __syncthreads();                 // all waves done reading main wlab
        if (tid < 64) wlab[tid] = (float)labels[c2 * 256 + t0 * 16 + tid];
        __syncthreads();

        run_cell(F, labels, S_all, S_1, wlab, r2, c2, false, t0, 4,
                 lane, l15, quad, wave);
    }
}

// ---------------------------------------------------------------------------
// finalize: fold 2048 sigma partials (redundantly per block, coalesced
// float4), then per-row losses + mean reduction into out[0].
// ---------------------------------------------------------------------------
__global__ __launch_bounds__(256) void finalize_kernel(
    const int* __restrict__ labels, const float* __restrict__ dist_sq,
    const float* __restrict__ S_all, const float* __restrict__ S_1,
    const float* __restrict__ stats_part, const float* __restrict__ rsigma,
    float* __restrict__ out)
{
    __shared__ float sh[3][4];
    const int lane = threadIdx.x & 63;
    const int wave = threadIdx.x >> 6;

    float c = 0.0f, s = 0.0f, q = 0.0f;
    const float4* sp = reinterpret_cast<const float4*>(stats_part);
    #pragma unroll
    for (int b = 0; b < 8; ++b) {
        const float4 v = sp[b * 256 + threadIdx.x];
        c += v.x; s += v.y; q += v.z;
    }
    #pragma unroll
    for (int m = 1; m < 64; m <<= 1) {
        c += __shfl_xor(c, m);
        s += __shfl_xor(s, m);
        q += __shfl_xor(q, m);
    }
    if (lane == 0) { sh[0][wave] = c; sh[1][wave] = s; sh[2][wave] = q; }
    __syncthreads();

    const float n0   = sh[0][0] + sh[0][1] + sh[0][2] + sh[0][3];
    const float ssx  = sh[1][0] + sh[1][1] + sh[1][2] + sh[1][3];
    const float snsq = sh[2][0] + sh[2][1] + sh[2][2] + sh[2][3];

    const float n_el = n0 * (float)DD;
    const float mean = ssx / n_el;
    const float var  = (snsq - n_el * mean * mean) / (n_el - 1.0f);
    const float sigma_new  = 0.9f * rsigma[0] + 0.1f * sqrtf(var);
    const float m_adaptive = 0.5f + 0.3f * sigma_new + 0.3f * (1.0f - 224.0f / 900.0f);

    const int i = blockIdx.x * 256 + threadIdx.x;
    const int l = labels[i];
    const float dsq = dist_sq[i];

    const float r_center = (l == 0) ? dsq : 0.0f;
    const float r_margin = (l == 1) ? fmaxf(m_adaptive - sqrtf(dsq), 0.0f) : 0.0f;

    const float sallv = S_all[i];
    const float s1v   = S_1[i];
    const float s0v   = sallv - s1v;
    const float pos = (l == 0) ? s0v : s1v;
    const float neg = (l == 0) ? s1v : s0v;

    const float n1 = (float)BB - n0;
    const float cnt_same = ((l == 0) ? n0 : n1) - 1.0f;
    const float cnt_diff = (l == 0) ? n1 : n0;

    float r_con = 0.0f;
    if (cnt_same > 0.0f && cnt_diff > 0.0f)
        r_con = logf(pos + neg + 1e-8f) - logf(pos);

    float tot = (r_center + r_margin + 0.5f * r_con) * (1.0f / (float)BB);

    #pragma unroll
    for (int m = 1; m < 64; m <<= 1) tot += __shfl_xor(tot, m);
    if ((threadIdx.x & 63) == 0) atomicAdd(out, tot);
}

// ---------------------------------------------------------------------------
// launch
// ---------------------------------------------------------------------------
extern "C" void kernel_launch(void* const* d_in, const int* in_sizes, int n_in,
                              void* d_out, int out_size, void* d_ws, size_t ws_size,
                              hipStream_t stream) {
    const float* feat   = (const float*)d_in[0];
    const int*   labels = (const int*)d_in[1];
    const float* center = (const float*)d_in[2];
    const float* rsigma = (const float*)d_in[3];
    float* out = (float*)d_out;

    char* ws = (char*)d_ws;
    __hip_bfloat16* fnf = (__hip_bfloat16*)ws;                    // B*D bf16 = 4 MB, fragment order
    float* dist_sq   = (float*)(ws + (size_t)BB * DD * 2);        // B floats
    float* S_all     = dist_sq + BB;                              // B floats
    float* S_1       = S_all + BB;                                // B floats
    float* stats_part= S_1 + BB;                                  // 2048*4 floats

    prep_kernel<<<dim3(BB / 4), dim3(256), 0, stream>>>(feat, labels, center, fnf,
                                                        dist_sq, stats_part, S_all, out);
    gram_kernel<<<dim3(1024), dim3(256), 0, stream>>>(fnf, labels, S_all, S_1);
    finalize_kernel<<<dim3(BB / 256), dim3(256), 0, stream>>>(labels, dist_sq, S_all, S_1,
                                                              stats_part, rsigma, out);
}

// Round 10
// 120.783 us; speedup vs baseline: 1.1570x; 1.1570x over previous
//
#include <hip/hip_runtime.h>
#include <hip/hip_bf16.h>

#define BB 8192
#define DD 256
#define ZN (2 * BB)   // floats to zero: S_all, S_1

typedef float f32x4 __attribute__((ext_vector_type(4)));
typedef __bf16 bf16x8 __attribute__((ext_vector_type(8)));

// sqrt(log2(e)/0.07): fn rows pre-scaled so MFMA acc = sim * log2(e)/T directly
#define FSCALE 4.53981600f

// raw v_exp_f32: args here are |x| <= ~21, no range fixup needed
__device__ __forceinline__ float fast_exp2(float x) {
    float r;
    asm("v_exp_f32 %0, %1" : "=v"(r) : "v"(x));
    return r;
}

// ---------------------------------------------------------------------------
// prep: one wave per row. dist_sq vs center, sigma partials (block-reduced,
// race-free into stats_part[block]), writes the normalized+scaled row in MFMA
// FRAGMENT ORDER. Also zeroes S_all/S_1/out.
// ---------------------------------------------------------------------------
__global__ __launch_bounds__(256) void prep_kernel(
    const float* __restrict__ feat, const int* __restrict__ labels,
    const float* __restrict__ center, __hip_bfloat16* __restrict__ fnf,
    float* __restrict__ dist_sq, float* __restrict__ stats_part,
    float* __restrict__ zacc, float* __restrict__ out)
{
    __shared__ float sh[3][4];
    const int gid = blockIdx.x * 256 + threadIdx.x;
    if (gid < ZN) zacc[gid] = 0.0f;
    if (gid == 0) out[0] = 0.0f;

    const int wave = threadIdx.x >> 6;
    const int lane = threadIdx.x & 63;
    const int row  = blockIdx.x * 4 + wave;

    const float4* frow = reinterpret_cast<const float4*>(feat + (size_t)row * DD);
    const float4* crow = reinterpret_cast<const float4*>(center);
    float4 x = frow[lane];
    float4 c = crow[lane];

    float d0 = x.x - c.x, d1 = x.y - c.y, d2 = x.z - c.z, d3 = x.w - c.w;
    float dsq = d0*d0 + d1*d1 + d2*d2 + d3*d3;
    float nsq = x.x*x.x + x.y*x.y + x.z*x.z + x.w*x.w;
    float sx  = x.x + x.y + x.z + x.w;

    #pragma unroll
    for (int m = 1; m < 64; m <<= 1) {
        dsq += __shfl_xor(dsq, m);
        nsq += __shfl_xor(nsq, m);
        sx  += __shfl_xor(sx,  m);
    }

    float rn = FSCALE / fmaxf(sqrtf(nsq), 1e-12f);

    ushort4 u;
    u.x = __builtin_bit_cast(unsigned short, __float2bfloat16(x.x * rn));
    u.y = __builtin_bit_cast(unsigned short, __float2bfloat16(x.y * rn));
    u.z = __builtin_bit_cast(unsigned short, __float2bfloat16(x.z * rn));
    u.w = __builtin_bit_cast(unsigned short, __float2bfloat16(x.w * rn));

    // lane holds elems e=4*lane..+3: kc=lane/8, quad=(lane%8)/2, half=lane&1
    const int g    = row >> 4;
    const int l15r = row & 15;
    const int kc   = lane >> 3;
    const int qd   = (lane & 7) >> 1;
    const int half = lane & 1;
    const size_t cell = (size_t)((g * 8 + kc) * 64 + qd * 16 + l15r);
    reinterpret_cast<ushort4*>(fnf)[cell * 2 + half] = u;

    if (lane == 0) {
        const float m0 = (labels[row] == 0) ? 1.0f : 0.0f;
        dist_sq[row] = dsq;
        sh[0][wave] = m0;
        sh[1][wave] = sx  * m0;
        sh[2][wave] = nsq * m0;
    }
    __syncthreads();
    if (threadIdx.x == 0) {
        float* sp = stats_part + (size_t)blockIdx.x * 4;
        sp[0] = sh[0][0] + sh[0][1] + sh[0][2] + sh[0][3];
        sp[1] = sh[1][0] + sh[1][1] + sh[1][2] + sh[1][3];
        sp[2] = sh[2][0] + sh[2][1] + sh[2][2] + sh[2][3];
        sp[3] = 0.0f;
    }
}

// ---------------------------------------------------------------------------
// gram v11: v9's symmetric kernel (proven correct, absmax 0) with the
// col-side sink moved to LDS wave-private bins.
// v9/v10 diagnosis: MFMA-halving real (MfmaUtil 29->12.5%), eaten by 2.03M
// per-lane global atomics (WRITE_SIZE 4->17->64 MB tracks atomics; cross-XCD
// line ping-pong). Fix: each lane's 8 acc values share ONE column, and each
// (wave,col) is visited by exactly one tile -> col partials are plain
// ds_writes into colbin[2][4][256] (8 KB, no contention, no init needed).
// One barrier after the loop; 256 threads fold 4 wave bins -> 512 global
// atomics/block (4x fewer, batched). Diag blocks skip col-side entirely.
// Grid 1056 (64 diag + 992 upper), pipeline/decode = v9 verbatim.
// ---------------------------------------------------------------------------
#define LOAD4(BV, T, KB)                                                       \
  {                                                                            \
    _Pragma("unroll")                                                          \
    for (int k = 0; k < 4; ++k)                                                \
      BV[k] = F[((size_t)(cpanel + (T)) * 8 + (KB) + k) * 64 + lane];          \
  }

#define MFMA8(BV, KB)                                                          \
  {                                                                            \
    _Pragma("unroll")                                                          \
    for (int k = 0; k < 4; ++k) {                                              \
      acc[0] = __builtin_amdgcn_mfma_f32_16x16x32_bf16(a[0][(KB) + k], BV[k], acc[0], 0, 0, 0); \
      acc[1] = __builtin_amdgcn_mfma_f32_16x16x32_bf16(a[1][(KB) + k], BV[k], acc[1], 0, 0, 0); \
    }                                                                          \
  }

#define EPILOGUE(T)                                                            \
  {                                                                            \
    const int colbase = colstart + (T) * 16;                                   \
    const int bcol = colbase + l15;                                            \
    const float w1 = wlab[(T) * 16 + l15];                                     \
    if (isdiag) {                                                              \
      if (colbase + 16 > rowbase && colbase < rowbase + 32) {                  \
        _Pragma("unroll")                                                      \
        for (int s = 0; s < 2; ++s)                                            \
          _Pragma("unroll")                                                    \
          for (int rr = 0; rr < 4; ++rr) {                                     \
            const int rq = rowbase + s * 16 + quad * 4 + rr;                   \
            float e = (rq == bcol) ? 0.0f : fast_exp2(acc[s][rr]);             \
            sall[s][rr] += e; sp1[s][rr] = fmaf(e, w1, sp1[s][rr]);            \
          }                                                                    \
      } else {                                                                 \
        _Pragma("unroll")                                                      \
        for (int s = 0; s < 2; ++s)                                            \
          _Pragma("unroll")                                                    \
          for (int rr = 0; rr < 4; ++rr) {                                     \
            float e = fast_exp2(acc[s][rr]);                                   \
            sall[s][rr] += e; sp1[s][rr] = fmaf(e, w1, sp1[s][rr]);            \
          }                                                                    \
      }                                                                        \
    } else {                                                                   \
      float ca = 0.0f, c1 = 0.0f;                                              \
      _Pragma("unroll")                                                        \
      for (int s = 0; s < 2; ++s)                                              \
        _Pragma("unroll")                                                      \
        for (int rr = 0; rr < 4; ++rr) {                                       \
          float e = fast_exp2(acc[s][rr]);                                     \
          sall[s][rr] += e; sp1[s][rr] = fmaf(e, w1, sp1[s][rr]);              \
          ca += e; c1 = fmaf(e, wr[s][rr], c1);                                \
        }                                                                      \
      ca += __shfl_xor(ca, 16); ca += __shfl_xor(ca, 32);                      \
      c1 += __shfl_xor(c1, 16); c1 += __shfl_xor(c1, 32);                      \
      if (quad == 0) {                                                         \
        colbin[0][wave][(T) * 16 + l15] = ca;                                  \
        colbin[1][wave][(T) * 16 + l15] = c1;                                  \
      }                                                                        \
    }                                                                          \
  }

__global__ __launch_bounds__(256, 4) void gram_kernel(
    const __hip_bfloat16* __restrict__ fnf, const int* __restrict__ labels,
    float* __restrict__ S_all, float* __restrict__ S_1)
{
    __shared__ float wlab[256];
    __shared__ float colbin[2][4][256];   // [array][wave][col] - 8 KB

    const int tid  = threadIdx.x;
    const int lane = tid & 63;
    const int wave = tid >> 6;
    const int l15  = lane & 15;
    const int quad = lane >> 4;

    // block -> (r, c): 64 diag blocks (r = bid, c = bid>>1), then upper list
    // for col-split c: 2c blocks at cumulative offset c*(c-1).
    const int bid = blockIdx.x;
    int r, c;
    bool isdiag;
    if (bid < 64) {
        r = bid; c = bid >> 1; isdiag = true;
    } else {
        const int e = bid - 64;
        int c0 = (int)((1.0f + sqrtf(1.0f + 4.0f * (float)e)) * 0.5f);
        while (c0 * (c0 - 1) > e) --c0;
        while ((c0 + 1) * c0 <= e) ++c0;
        c = c0; r = e - c0 * (c0 - 1); isdiag = false;
    }

    const int rowbase  = r * 128 + wave * 32;
    const int colstart = c * 256;
    const int cpanel   = colstart >> 4;  // first 16-col cell group

    const bf16x8* __restrict__ F = reinterpret_cast<const bf16x8*>(fnf);

    // A fragments: 2 sub-tiles x 8 k-chunks = 32 rows/wave, coalesced loads
    bf16x8 a[2][8];
    #pragma unroll
    for (int s = 0; s < 2; ++s)
        #pragma unroll
        for (int kc = 0; kc < 8; ++kc)
            a[s][kc] = F[(size_t)((((rowbase >> 4) + s) * 8 + kc)) * 64 + lane];

    // row labels for this lane's 8 accumulator rows (col-side S_1 weights)
    float wr[2][4];
    #pragma unroll
    for (int s = 0; s < 2; ++s)
        #pragma unroll
        for (int rr = 0; rr < 4; ++rr)
            wr[s][rr] = (float)labels[rowbase + s * 16 + quad * 4 + rr];

    float sall[2][4], sp1[2][4];
    #pragma unroll
    for (int s = 0; s < 2; ++s)
        #pragma unroll
        for (int rr = 0; rr < 4; ++rr) { sall[s][rr] = 0.0f; sp1[s][rr] = 0.0f; }

    wlab[tid] = (float)labels[colstart + tid];
    __syncthreads();        // wlab ready; waves de-phase after this

    f32x4 acc[2];
    bf16x8 bvP[4], bvC[4];  // fixed roles: bvP = lo(next), bvC = hi(current)

    LOAD4(bvP, 0, 0);       // prefetch tile 0 lo-half

    #pragma unroll 1
    for (int t = 0; t < 15; ++t) {
        LOAD4(bvC, t, 4);           // current hi-half, in flight under MFMA-lo
        acc[0] = (f32x4){0,0,0,0}; acc[1] = (f32x4){0,0,0,0};
        MFMA8(bvP, 0);              // consume lo (prefetched last tile)
        LOAD4(bvP, t + 1, 0);       // prefetch next lo (WAR: after consume)
        MFMA8(bvC, 4);              // vmcnt wait for bvC folds under MFMA-lo
        EPILOGUE(t);
    }
    // t == 15
    LOAD4(bvC, 15, 4);
    acc[0] = (f32x4){0,0,0,0}; acc[1] = (f32x4){0,0,0,0};
    MFMA8(bvP, 0);
    MFMA8(bvC, 4);
    EPILOGUE(15);

    // row-side: reduce over the 16 cols held across low lane bits
    #pragma unroll
    for (int s = 0; s < 2; ++s)
        #pragma unroll
        for (int rr = 0; rr < 4; ++rr) {
            float va = sall[s][rr];
            float v1 = sp1[s][rr];
            #pragma unroll
            for (int m = 1; m < 16; m <<= 1) {
                va += __shfl_xor(va, m);
                v1 += __shfl_xor(v1, m);
            }
            if (l15 == 0) {
                const int grow = rowbase + s * 16 + quad * 4 + rr;
                atomicAdd(&S_all[grow], va);
                atomicAdd(&S_1[grow],  v1);
            }
        }

    // col-side fold: 4 wave bins -> 2 global atomics per col (upper only)
    if (!isdiag) {
        __syncthreads();    // all waves' colbin writes complete
        const float fa = colbin[0][0][tid] + colbin[0][1][tid]
                       + colbin[0][2][tid] + colbin[0][3][tid];
        const float f1 = colbin[1][0][tid] + colbin[1][1][tid]
                       + colbin[1][2][tid] + colbin[1][3][tid];
        atomicAdd(&S_all[colstart + tid], fa);
        atomicAdd(&S_1[colstart + tid],  f1);
    }
}

// ---------------------------------------------------------------------------
// finalize: fold 2048 sigma partials (redundantly per block, coalesced
// float4), then per-row losses + mean reduction into out[0].
// ---------------------------------------------------------------------------
__global__ __launch_bounds__(256) void finalize_kernel(
    const int* __restrict__ labels, const float* __restrict__ dist_sq,
    const float* __restrict__ S_all, const float* __restrict__ S_1,
    const float* __restrict__ stats_part, const float* __restrict__ rsigma,
    float* __restrict__ out)
{
    __shared__ float sh[3][4];
    const int lane = threadIdx.x & 63;
    const int wave = threadIdx.x >> 6;

    float c = 0.0f, s = 0.0f, q = 0.0f;
    const float4* sp = reinterpret_cast<const float4*>(stats_part);
    #pragma unroll
    for (int b = 0; b < 8; ++b) {
        const float4 v = sp[b * 256 + threadIdx.x];
        c += v.x; s += v.y; q += v.z;
    }
    #pragma unroll
    for (int m = 1; m < 64; m <<= 1) {
        c += __shfl_xor(c, m);
        s += __shfl_xor(s, m);
        q += __shfl_xor(q, m);
    }
    if (lane == 0) { sh[0][wave] = c; sh[1][wave] = s; sh[2][wave] = q; }
    __syncthreads();

    const float n0   = sh[0][0] + sh[0][1] + sh[0][2] + sh[0][3];
    const float ssx  = sh[1][0] + sh[1][1] + sh[1][2] + sh[1][3];
    const float snsq = sh[2][0] + sh[2][1] + sh[2][2] + sh[2][3];

    const float n_el = n0 * (float)DD;
    const float mean = ssx / n_el;
    const float var  = (snsq - n_el * mean * mean) / (n_el - 1.0f);
    const float sigma_new  = 0.9f * rsigma[0] + 0.1f * sqrtf(var);
    const float m_adaptive = 0.5f + 0.3f * sigma_new + 0.3f * (1.0f - 224.0f / 900.0f);

    const int i = blockIdx.x * 256 + threadIdx.x;
    const int l = labels[i];
    const float dsq = dist_sq[i];

    const float r_center = (l == 0) ? dsq : 0.0f;
    const float r_margin = (l == 1) ? fmaxf(m_adaptive - sqrtf(dsq), 0.0f) : 0.0f;

    const float sallv = S_all[i];
    const float s1v   = S_1[i];
    const float s0v   = sallv - s1v;
    const float pos = (l == 0) ? s0v : s1v;
    const float neg = (l == 0) ? s1v : s0v;

    const float n1 = (float)BB - n0;
    const float cnt_same = ((l == 0) ? n0 : n1) - 1.0f;
    const float cnt_diff = (l == 0) ? n1 : n0;

    float r_con = 0.0f;
    if (cnt_same > 0.0f && cnt_diff > 0.0f)
        r_con = logf(pos + neg + 1e-8f) - logf(pos);

    float tot = (r_center + r_margin + 0.5f * r_con) * (1.0f / (float)BB);

    #pragma unroll
    for (int m = 1; m < 64; m <<= 1) tot += __shfl_xor(tot, m);
    if ((threadIdx.x & 63) == 0) atomicAdd(out, tot);
}

// ---------------------------------------------------------------------------
// launch
// ---------------------------------------------------------------------------
extern "C" void kernel_launch(void* const* d_in, const int* in_sizes, int n_in,
                              void* d_out, int out_size, void* d_ws, size_t ws_size,
                              hipStream_t stream) {
    const float* feat   = (const float*)d_in[0];
    const int*   labels = (const int*)d_in[1];
    const float* center = (const float*)d_in[2];
    const float* rsigma = (const float*)d_in[3];
    float* out = (float*)d_out;

    char* ws = (char*)d_ws;
    __hip_bfloat16* fnf = (__hip_bfloat16*)ws;                    // B*D bf16 = 4 MB, fragment order
    float* dist_sq   = (float*)(ws + (size_t)BB * DD * 2);        // B floats
    float* S_all     = dist_sq + BB;                              // B floats
    float* S_1       = S_all + BB;                                // B floats
    float* stats_part= S_1 + BB;                                  // 2048*4 floats

    prep_kernel<<<dim3(BB / 4), dim3(256), 0, stream>>>(feat, labels, center, fnf,
                                                        dist_sq, stats_part, S_all, out);
    gram_kernel<<<dim3(1056), dim3(256), 0, stream>>>(fnf, labels, S_all, S_1);
    finalize_kernel<<<dim3(BB / 256), dim3(256), 0, stream>>>(labels, dist_sq, S_all, S_1,
                                                              stats_part, rsigma, out);
}